// Round 1
// baseline (1576.555 us; speedup 1.0000x reference)
//
#include <hip/hip_runtime.h>

#define M_NODES  50000
#define D_IN_K   512
#define D_OUT_N  128
#define N_EDGES  800000

// ---------------------------------------------------------------------------
// Kernel 1: h = x @ W   (fp32, VALU; no fp32 MFMA on CDNA4)
// Tile: BM=64 rows, BN=128 (all cols), BK=32. 256 threads.
// Thread tile: TM=8 rows x TN=4 cols = 32 acc regs.
// ---------------------------------------------------------------------------
__global__ __launch_bounds__(256) void gemm_kernel(const float* __restrict__ x,
                                                   const float* __restrict__ W,
                                                   float* __restrict__ h) {
    // xs transposed [k][m], stride 68 keeps float4 reads 16B-aligned (68*4=272=17*16)
    __shared__ float xs[32][68];
    __shared__ float ws[32][D_OUT_N];

    const int tid = threadIdx.x;
    const int tx  = tid & 31;   // col group: cols tx*4 .. tx*4+3
    const int ty  = tid >> 5;   // row group: rows ty*8 .. ty*8+7
    const int m0  = blockIdx.x * 64;

    float acc[8][4];
#pragma unroll
    for (int r = 0; r < 8; ++r)
#pragma unroll
        for (int c = 0; c < 4; ++c) acc[r][c] = 0.f;

    for (int kb = 0; kb < D_IN_K; kb += 32) {
        // --- stage x tile (64 rows x 32 k), transposed into LDS ---
#pragma unroll
        for (int i = 0; i < 2; ++i) {
            int slot = tid + i * 256;          // 0..511 float4 slots
            int row  = slot >> 3;              // 0..63
            int kg   = slot & 7;               // float4 group along k
            float4 v = make_float4(0.f, 0.f, 0.f, 0.f);
            if (m0 + row < M_NODES)
                v = *(const float4*)&x[(size_t)(m0 + row) * D_IN_K + kb + kg * 4];
            xs[kg * 4 + 0][row] = v.x;
            xs[kg * 4 + 1][row] = v.y;
            xs[kg * 4 + 2][row] = v.z;
            xs[kg * 4 + 3][row] = v.w;
        }
        // --- stage W tile (32 k x 128 n) ---
#pragma unroll
        for (int i = 0; i < 4; ++i) {
            int slot = tid + i * 256;          // 0..1023 float4 slots
            int row  = slot >> 5;              // k row 0..31
            int cg   = slot & 31;              // float4 col group
            *(float4*)&ws[row][cg * 4] =
                *(const float4*)&W[(size_t)(kb + row) * D_OUT_N + cg * 4];
        }
        __syncthreads();

#pragma unroll
        for (int kk = 0; kk < 32; ++kk) {
            float4 a0 = *(const float4*)&xs[kk][ty * 8];
            float4 a1 = *(const float4*)&xs[kk][ty * 8 + 4];
            float4 wv = *(const float4*)&ws[kk][tx * 4];
            float a[8] = {a0.x, a0.y, a0.z, a0.w, a1.x, a1.y, a1.z, a1.w};
            float wc[4] = {wv.x, wv.y, wv.z, wv.w};
#pragma unroll
            for (int r = 0; r < 8; ++r)
#pragma unroll
                for (int c = 0; c < 4; ++c)
                    acc[r][c] += a[r] * wc[c];
        }
        __syncthreads();
    }

#pragma unroll
    for (int r = 0; r < 8; ++r) {
        int row = m0 + ty * 8 + r;
        if (row < M_NODES)
            *(float4*)&h[(size_t)row * D_OUT_N + tx * 4] =
                make_float4(acc[r][0], acc[r][1], acc[r][2], acc[r][3]);
    }
}

// ---------------------------------------------------------------------------
// Kernel 2: out[i][j] = b[j]   (d_out is poisoned before every call)
// ---------------------------------------------------------------------------
__global__ __launch_bounds__(256) void init_kernel(const float* __restrict__ b,
                                                   float* __restrict__ out) {
    int tid = blockIdx.x * blockDim.x + threadIdx.x;   // float4 slot
    if (tid >= M_NODES * (D_OUT_N / 4)) return;
    int cg = tid & 31;
    float4 bv = *(const float4*)&b[cg * 4];
    *(float4*)&out[(size_t)tid * 4] = bv;
}

// ---------------------------------------------------------------------------
// Kernel 3: scatter-aggregate. 32 lanes per edge; float4 gather of h[src],
// 4 scalar f32 atomics into out[dst].
// ---------------------------------------------------------------------------
__global__ __launch_bounds__(256) void scatter_kernel(const float* __restrict__ h,
                                                      const float* __restrict__ edge_w,
                                                      const int* __restrict__ src,
                                                      const int* __restrict__ dst,
                                                      float* __restrict__ out) {
    long long tid = (long long)blockIdx.x * blockDim.x + threadIdx.x;
    int e    = (int)(tid >> 5);
    int lane = (int)(tid & 31);
    if (e >= N_EDGES) return;
    int   s = src[e];
    int   d = dst[e];
    float w = edge_w[e];
    float4 hv = *(const float4*)&h[(size_t)s * D_OUT_N + lane * 4];
    float* op = &out[(size_t)d * D_OUT_N + lane * 4];
    atomicAdd(op + 0, w * hv.x);
    atomicAdd(op + 1, w * hv.y);
    atomicAdd(op + 2, w * hv.z);
    atomicAdd(op + 3, w * hv.w);
}

extern "C" void kernel_launch(void* const* d_in, const int* in_sizes, int n_in,
                              void* d_out, int out_size, void* d_ws, size_t ws_size,
                              hipStream_t stream) {
    const float* x      = (const float*)d_in[0];
    const float* edge_w = (const float*)d_in[1];
    const int*   src    = (const int*)d_in[2];
    const int*   dst    = (const int*)d_in[3];
    const float* W      = (const float*)d_in[4];
    const float* b      = (const float*)d_in[5];
    float* out = (float*)d_out;
    float* h   = (float*)d_ws;   // 50000*128*4 = 25.6 MB

    gemm_kernel<<<(M_NODES + 63) / 64, 256, 0, stream>>>(x, W, h);
    init_kernel<<<(M_NODES * (D_OUT_N / 4) + 255) / 256, 256, 0, stream>>>(b, out);
    scatter_kernel<<<(int)(((long long)N_EDGES * 32 + 255) / 256), 256, 0, stream>>>(
        h, edge_w, src, dst, out);
}

// Round 2
// 429.653 us; speedup vs baseline: 3.6694x; 3.6694x over previous
//
#include <hip/hip_runtime.h>

#define M_NODES  50000
#define D_IN_K   512
#define D_OUT_N  128
#define N_EDGES  800000

// ---------------------------------------------------------------------------
// Kernel 1: h = x @ W   (fp32, VALU; no fp32 MFMA on CDNA4)
// ---------------------------------------------------------------------------
__global__ __launch_bounds__(256) void gemm_kernel(const float* __restrict__ x,
                                                   const float* __restrict__ W,
                                                   float* __restrict__ h) {
    __shared__ float xs[32][68];
    __shared__ float ws[32][D_OUT_N];

    const int tid = threadIdx.x;
    const int tx  = tid & 31;
    const int ty  = tid >> 5;
    const int m0  = blockIdx.x * 64;

    float acc[8][4];
#pragma unroll
    for (int r = 0; r < 8; ++r)
#pragma unroll
        for (int c = 0; c < 4; ++c) acc[r][c] = 0.f;

    for (int kb = 0; kb < D_IN_K; kb += 32) {
#pragma unroll
        for (int i = 0; i < 2; ++i) {
            int slot = tid + i * 256;
            int row  = slot >> 3;
            int kg   = slot & 7;
            float4 v = make_float4(0.f, 0.f, 0.f, 0.f);
            if (m0 + row < M_NODES)
                v = *(const float4*)&x[(size_t)(m0 + row) * D_IN_K + kb + kg * 4];
            xs[kg * 4 + 0][row] = v.x;
            xs[kg * 4 + 1][row] = v.y;
            xs[kg * 4 + 2][row] = v.z;
            xs[kg * 4 + 3][row] = v.w;
        }
#pragma unroll
        for (int i = 0; i < 4; ++i) {
            int slot = tid + i * 256;
            int row  = slot >> 5;
            int cg   = slot & 31;
            *(float4*)&ws[row][cg * 4] =
                *(const float4*)&W[(size_t)(kb + row) * D_OUT_N + cg * 4];
        }
        __syncthreads();

#pragma unroll
        for (int kk = 0; kk < 32; ++kk) {
            float4 a0 = *(const float4*)&xs[kk][ty * 8];
            float4 a1 = *(const float4*)&xs[kk][ty * 8 + 4];
            float4 wv = *(const float4*)&ws[kk][tx * 4];
            float a[8] = {a0.x, a0.y, a0.z, a0.w, a1.x, a1.y, a1.z, a1.w};
            float wc[4] = {wv.x, wv.y, wv.z, wv.w};
#pragma unroll
            for (int r = 0; r < 8; ++r)
#pragma unroll
                for (int c = 0; c < 4; ++c)
                    acc[r][c] += a[r] * wc[c];
        }
        __syncthreads();
    }

#pragma unroll
    for (int r = 0; r < 8; ++r) {
        int row = m0 + ty * 8 + r;
        if (row < M_NODES)
            *(float4*)&h[(size_t)row * D_OUT_N + tx * 4] =
                make_float4(acc[r][0], acc[r][1], acc[r][2], acc[r][3]);
    }
}

// ---------------------------------------------------------------------------
// CSR build: zero counts -> histogram -> exclusive scan -> permute edges
// ---------------------------------------------------------------------------
__global__ __launch_bounds__(256) void zero_kernel(int* __restrict__ counts) {
    int i = blockIdx.x * blockDim.x + threadIdx.x;
    if (i < M_NODES) counts[i] = 0;
}

__global__ __launch_bounds__(256) void hist_kernel(const int* __restrict__ dst,
                                                   int* __restrict__ counts) {
    int e = blockIdx.x * blockDim.x + threadIdx.x;
    if (e < N_EDGES) atomicAdd(&counts[dst[e]], 1);
}

// Single-block exclusive scan of counts[0..M_NODES) -> offsets, cursor.
// 1024 threads, running carry across chunks.
__global__ __launch_bounds__(1024) void scan_kernel(const int* __restrict__ counts,
                                                    int* __restrict__ offsets,
                                                    int* __restrict__ cursor) {
    __shared__ int wave_sums[16];
    const int tid  = threadIdx.x;
    const int lane = tid & 63;
    const int wid  = tid >> 6;
    int carry = 0;
    for (int base = 0; base < M_NODES; base += 1024) {
        int idx = base + tid;
        int v = (idx < M_NODES) ? counts[idx] : 0;
        // inclusive scan within wave (64 lanes)
        int s = v;
#pragma unroll
        for (int d = 1; d < 64; d <<= 1) {
            int t = __shfl_up(s, d, 64);
            if (lane >= d) s += t;
        }
        if (lane == 63) wave_sums[wid] = s;
        __syncthreads();
        if (wid == 0 && lane < 16) {
            int wsv = wave_sums[lane];
#pragma unroll
            for (int d = 1; d < 16; d <<= 1) {
                int t = __shfl_up(wsv, d, 64);
                if (lane >= d) wsv += t;
            }
            wave_sums[lane] = wsv;  // inclusive scan of wave totals
        }
        __syncthreads();
        int wave_off = (wid == 0) ? 0 : wave_sums[wid - 1];
        int excl = s + wave_off + carry - v;
        if (idx < M_NODES) { offsets[idx] = excl; cursor[idx] = excl; }
        int total = wave_sums[15];
        __syncthreads();  // protect wave_sums before next chunk
        carry += total;
    }
    if (tid == 0) offsets[M_NODES] = carry;  // == N_EDGES
}

// Scatter edge records into CSR order: ep[pos] = (src[e], bits(edge_w[e]))
__global__ __launch_bounds__(256) void fill_kernel(const int* __restrict__ src,
                                                   const int* __restrict__ dst,
                                                   const float* __restrict__ edge_w,
                                                   int* __restrict__ cursor,
                                                   int2* __restrict__ ep) {
    int e = blockIdx.x * blockDim.x + threadIdx.x;
    if (e >= N_EDGES) return;
    int d   = dst[e];
    int pos = atomicAdd(&cursor[d], 1);
    ep[pos] = make_int2(src[e], __float_as_int(edge_w[e]));
}

// ---------------------------------------------------------------------------
// Gather: out[i] = b + sum_{e in CSR row i} w_e * h[src_e].  32 lanes/node.
// ---------------------------------------------------------------------------
__global__ __launch_bounds__(256) void gather_kernel(const float* __restrict__ h,
                                                     const int2* __restrict__ ep,
                                                     const int* __restrict__ offsets,
                                                     const float* __restrict__ b,
                                                     float* __restrict__ out) {
    int node = (int)((blockIdx.x * (long long)blockDim.x + threadIdx.x) >> 5);
    int lane = threadIdx.x & 31;
    if (node >= M_NODES) return;
    int beg = offsets[node];
    int end = offsets[node + 1];
    float4 acc = *(const float4*)&b[lane * 4];
    for (int j = beg; j < end; ++j) {
        int2  er = ep[j];                     // broadcast across the 32 lanes
        float w  = __int_as_float(er.y);
        float4 hv = *(const float4*)&h[(size_t)er.x * D_OUT_N + lane * 4];
        acc.x += w * hv.x;
        acc.y += w * hv.y;
        acc.z += w * hv.z;
        acc.w += w * hv.w;
    }
    *(float4*)&out[(size_t)node * D_OUT_N + lane * 4] = acc;
}

extern "C" void kernel_launch(void* const* d_in, const int* in_sizes, int n_in,
                              void* d_out, int out_size, void* d_ws, size_t ws_size,
                              hipStream_t stream) {
    const float* x      = (const float*)d_in[0];
    const float* edge_w = (const float*)d_in[1];
    const int*   src    = (const int*)d_in[2];
    const int*   dst    = (const int*)d_in[3];
    const float* W      = (const float*)d_in[4];
    const float* b      = (const float*)d_in[5];
    float* out = (float*)d_out;

    // workspace layout (16B-aligned chunks)
    char* wsp = (char*)d_ws;
    float* h       = (float*)wsp;                      wsp += (size_t)M_NODES * D_OUT_N * 4;  // 25.6 MB
    int*   counts  = (int*)wsp;                        wsp += ((size_t)M_NODES * 4 + 15) & ~15ull;
    int*   offsets = (int*)wsp;                        wsp += (((size_t)M_NODES + 1) * 4 + 15) & ~15ull;
    int*   cursor  = (int*)wsp;                        wsp += ((size_t)M_NODES * 4 + 15) & ~15ull;
    int2*  ep      = (int2*)wsp;                       wsp += (size_t)N_EDGES * 8;             // 6.4 MB

    gemm_kernel<<<(M_NODES + 63) / 64, 256, 0, stream>>>(x, W, h);
    zero_kernel<<<(M_NODES + 255) / 256, 256, 0, stream>>>(counts);
    hist_kernel<<<(N_EDGES + 255) / 256, 256, 0, stream>>>(dst, counts);
    scan_kernel<<<1, 1024, 0, stream>>>(counts, offsets, cursor);
    fill_kernel<<<(N_EDGES + 255) / 256, 256, 0, stream>>>(src, dst, edge_w, cursor, ep);
    gather_kernel<<<(int)(((long long)M_NODES * 32 + 255) / 256), 256, 0, stream>>>(
        h, ep, offsets, b, out);
}

// Round 3
// 352.848 us; speedup vs baseline: 4.4681x; 1.2177x over previous
//
#include <hip/hip_runtime.h>

#define M_NODES  50000
#define D_IN_K   512
#define D_OUT_N  128
#define N_EDGES  800000
#define SCAN_NBLK 49   // ceil(50000/1024)

typedef short  bf16x8 __attribute__((ext_vector_type(8)));
typedef float  f32x4  __attribute__((ext_vector_type(4)));

static __device__ __forceinline__ unsigned short f2bf(float f) {
    unsigned u = __float_as_uint(f);
    unsigned r = u + 0x7FFF + ((u >> 16) & 1);   // RNE
    return (unsigned short)(r >> 16);
}

// ---------------------------------------------------------------------------
// Pre-permute W (fp32 [512][128]) into bf16 B-fragment order:
// Wp[((kb4*8 + nt)*64 + lane)*8 + j] = bf16(W[kb4*32 + (lane>>4)*8 + j][nt*16 + (lane&15)])
// 8192 threads, each writes one 16B frag.
// ---------------------------------------------------------------------------
__global__ __launch_bounds__(256) void permute_w_kernel(const float* __restrict__ W,
                                                        unsigned short* __restrict__ Wp) {
    int tid = blockIdx.x * blockDim.x + threadIdx.x;  // 0..8191
    if (tid >= 16 * 8 * 64) return;
    int lane = tid & 63;
    int nt   = (tid >> 6) & 7;
    int kb4  = tid >> 9;
    int n    = nt * 16 + (lane & 15);
    int kbase = kb4 * 32 + ((lane >> 4) & 3) * 8;
    unsigned short frag[8];
#pragma unroll
    for (int j = 0; j < 8; ++j)
        frag[j] = f2bf(W[(size_t)(kbase + j) * D_OUT_N + n]);
    *(uint4*)&Wp[(size_t)tid * 8] = *(const uint4*)frag;
}

// ---------------------------------------------------------------------------
// h = x @ W via bf16 MFMA 16x16x32. Block = 256 thr = 4 waves; wave = 16 rows,
// all 128 cols (8 tiles). A frags straight from global (fp32 -> bf16), B frags
// from pre-permuted Wp (L2-resident). No LDS.
// ---------------------------------------------------------------------------
__global__ __launch_bounds__(256) void mfma_gemm_kernel(const float* __restrict__ x,
                                                        const unsigned short* __restrict__ Wp,
                                                        float* __restrict__ h) {
    const int wave = threadIdx.x >> 6;
    const int lane = threadIdx.x & 63;
    const int m0   = blockIdx.x * 64 + wave * 16;
    if (m0 >= M_NODES) return;

    const int arow   = m0 + (lane & 15);
    const int rclamp = (arow < M_NODES) ? arow : (M_NODES - 1);
    const int kgrp   = lane >> 4;                  // 0..3
    const float* xrow = x + (size_t)rclamp * D_IN_K + kgrp * 8;

    f32x4 acc[8];
#pragma unroll
    for (int t = 0; t < 8; ++t) acc[t] = (f32x4){0.f, 0.f, 0.f, 0.f};

#pragma unroll 4
    for (int kb4 = 0; kb4 < 16; ++kb4) {
        float4 alo = *(const float4*)(xrow + kb4 * 32);
        float4 ahi = *(const float4*)(xrow + kb4 * 32 + 4);
        unsigned short af[8] = {f2bf(alo.x), f2bf(alo.y), f2bf(alo.z), f2bf(alo.w),
                                f2bf(ahi.x), f2bf(ahi.y), f2bf(ahi.z), f2bf(ahi.w)};
        bf16x8 a = *(const bf16x8*)af;
        const unsigned short* wp = Wp + ((size_t)(kb4 * 8) * 64 + lane) * 8;
#pragma unroll
        for (int nt = 0; nt < 8; ++nt) {
            bf16x8 b = *(const bf16x8*)(wp + (size_t)nt * 64 * 8);
            acc[nt] = __builtin_amdgcn_mfma_f32_16x16x32_bf16(a, b, acc[nt], 0, 0, 0);
        }
    }

    // C/D layout: col = lane&15, row = (lane>>4)*4 + r
    const int col = lane & 15;
#pragma unroll
    for (int r = 0; r < 4; ++r) {
        int rr = m0 + kgrp * 4 + r;
        if (rr < M_NODES) {
            float* hp = &h[(size_t)rr * D_OUT_N + col];
#pragma unroll
            for (int nt = 0; nt < 8; ++nt)
                hp[nt * 16] = acc[nt][r];
        }
    }
}

// ---------------------------------------------------------------------------
// CSR build
// ---------------------------------------------------------------------------
__global__ __launch_bounds__(256) void zero_kernel(int* __restrict__ counts) {
    int i = blockIdx.x * blockDim.x + threadIdx.x;
    if (i < M_NODES) counts[i] = 0;
}

__global__ __launch_bounds__(256) void hist_kernel(const int* __restrict__ dst,
                                                   int* __restrict__ counts) {
    int e = blockIdx.x * blockDim.x + threadIdx.x;
    if (e < N_EDGES) atomicAdd(&counts[dst[e]], 1);
}

// Multi-block scan, stage 1: per-block (1024 elems) exclusive scan + partial.
__global__ __launch_bounds__(256) void scan_partial_kernel(const int* __restrict__ counts,
                                                           int* __restrict__ offsets,
                                                           int* __restrict__ partials) {
    __shared__ int wsum[4];
    const int tid  = threadIdx.x;
    const int lane = tid & 63;
    const int wid  = tid >> 6;
    const int base = blockIdx.x * 1024 + tid * 4;

    int v[4];
#pragma unroll
    for (int i = 0; i < 4; ++i) v[i] = (base + i < M_NODES) ? counts[base + i] : 0;
    int t = v[0] + v[1] + v[2] + v[3];

    int s = t;
#pragma unroll
    for (int d = 1; d < 64; d <<= 1) {
        int u = __shfl_up(s, d, 64);
        if (lane >= d) s += u;
    }
    if (lane == 63) wsum[wid] = s;
    __syncthreads();
    int wbase = 0;
#pragma unroll
    for (int w = 0; w < 4; ++w) wbase += (w < wid) ? wsum[w] : 0;

    int run = wbase + s - t;
#pragma unroll
    for (int i = 0; i < 4; ++i) {
        if (base + i < M_NODES) offsets[base + i] = run;
        run += v[i];
    }
    if (tid == 255) partials[blockIdx.x] = wbase + s;
}

// Stage 2: scan the 49 partials (1 block, 64 threads).
__global__ __launch_bounds__(64) void scan_carry_kernel(const int* __restrict__ partials,
                                                        int* __restrict__ carries,
                                                        int* __restrict__ offsets) {
    int lane = threadIdx.x;
    int v = (lane < SCAN_NBLK) ? partials[lane] : 0;
    int s = v;
#pragma unroll
    for (int d = 1; d < 64; d <<= 1) {
        int u = __shfl_up(s, d, 64);
        if (lane >= d) s += u;
    }
    if (lane < SCAN_NBLK) carries[lane] = s - v;
    if (lane == 63) offsets[M_NODES] = s;   // total = N_EDGES
}

// Stage 3: add carries, fill cursor.
__global__ __launch_bounds__(256) void scan_add_kernel(int* __restrict__ offsets,
                                                       const int* __restrict__ carries,
                                                       int* __restrict__ cursor) {
    const int base = blockIdx.x * 1024 + threadIdx.x * 4;
    const int c = carries[blockIdx.x];
#pragma unroll
    for (int i = 0; i < 4; ++i) {
        if (base + i < M_NODES) {
            int o = offsets[base + i] + c;
            offsets[base + i] = o;
            cursor[base + i] = o;
        }
    }
}

// Permute edges into CSR order.
__global__ __launch_bounds__(256) void fill_kernel(const int* __restrict__ src,
                                                   const int* __restrict__ dst,
                                                   const float* __restrict__ edge_w,
                                                   int* __restrict__ cursor,
                                                   int2* __restrict__ ep) {
    int e = blockIdx.x * blockDim.x + threadIdx.x;
    if (e >= N_EDGES) return;
    int d   = dst[e];
    int pos = atomicAdd(&cursor[d], 1);
    ep[pos] = make_int2(src[e], __float_as_int(edge_w[e]));
}

// ---------------------------------------------------------------------------
// Gather: out[i] = b + sum_{e in row i} w_e * h[src_e]. 32 lanes/node.
// ---------------------------------------------------------------------------
__global__ __launch_bounds__(256) void gather_kernel(const float* __restrict__ h,
                                                     const int2* __restrict__ ep,
                                                     const int* __restrict__ offsets,
                                                     const float* __restrict__ b,
                                                     float* __restrict__ out) {
    int node = (int)((blockIdx.x * (long long)blockDim.x + threadIdx.x) >> 5);
    int lane = threadIdx.x & 31;
    if (node >= M_NODES) return;
    int beg = offsets[node];
    int end = offsets[node + 1];
    float4 acc = *(const float4*)&b[lane * 4];
    for (int j = beg; j < end; ++j) {
        int2  er = ep[j];
        float w  = __int_as_float(er.y);
        float4 hv = *(const float4*)&h[(size_t)er.x * D_OUT_N + lane * 4];
        acc.x += w * hv.x;
        acc.y += w * hv.y;
        acc.z += w * hv.z;
        acc.w += w * hv.w;
    }
    *(float4*)&out[(size_t)node * D_OUT_N + lane * 4] = acc;
}

extern "C" void kernel_launch(void* const* d_in, const int* in_sizes, int n_in,
                              void* d_out, int out_size, void* d_ws, size_t ws_size,
                              hipStream_t stream) {
    const float* x      = (const float*)d_in[0];
    const float* edge_w = (const float*)d_in[1];
    const int*   src    = (const int*)d_in[2];
    const int*   dst    = (const int*)d_in[3];
    const float* W      = (const float*)d_in[4];
    const float* b      = (const float*)d_in[5];
    float* out = (float*)d_out;

    char* wsp = (char*)d_ws;
    float* h        = (float*)wsp;       wsp += (size_t)M_NODES * D_OUT_N * 4;            // 25.6 MB
    int*   counts   = (int*)wsp;         wsp += ((size_t)M_NODES * 4 + 15) & ~15ull;
    int*   offsets  = (int*)wsp;         wsp += (((size_t)M_NODES + 1) * 4 + 15) & ~15ull;
    int*   cursor   = (int*)wsp;         wsp += ((size_t)M_NODES * 4 + 15) & ~15ull;
    int2*  ep       = (int2*)wsp;        wsp += (size_t)N_EDGES * 8;                      // 6.4 MB
    unsigned short* Wp = (unsigned short*)wsp; wsp += (size_t)16 * 8 * 64 * 8 * 2;        // 128 KB
    int*   partials = (int*)wsp;         wsp += (SCAN_NBLK * 4 + 15) & ~15ull;
    int*   carries  = (int*)wsp;         wsp += (SCAN_NBLK * 4 + 15) & ~15ull;

    permute_w_kernel<<<(16 * 8 * 64 + 255) / 256, 256, 0, stream>>>(W, Wp);
    mfma_gemm_kernel<<<(M_NODES + 63) / 64, 256, 0, stream>>>(x, Wp, h);
    zero_kernel<<<(M_NODES + 255) / 256, 256, 0, stream>>>(counts);
    hist_kernel<<<(N_EDGES + 255) / 256, 256, 0, stream>>>(dst, counts);
    scan_partial_kernel<<<SCAN_NBLK, 256, 0, stream>>>(counts, offsets, partials);
    scan_carry_kernel<<<1, 64, 0, stream>>>(partials, carries, offsets);
    scan_add_kernel<<<SCAN_NBLK, 256, 0, stream>>>(offsets, carries, cursor);
    fill_kernel<<<(N_EDGES + 255) / 256, 256, 0, stream>>>(src, dst, edge_w, cursor, ep);
    gather_kernel<<<(int)(((long long)M_NODES * 32 + 255) / 256), 256, 0, stream>>>(
        h, ep, offsets, b, out);
}

// Round 4
// 333.810 us; speedup vs baseline: 4.7229x; 1.0570x over previous
//
#include <hip/hip_runtime.h>
#include <hip/hip_bf16.h>

#define M_NODES  50000
#define D_IN_K   512
#define D_OUT_N  128
#define N_EDGES  800000
#define SCAN_NBLK 49   // ceil(50000/1024)

typedef short  bf16x8 __attribute__((ext_vector_type(8)));
typedef float  f32x4  __attribute__((ext_vector_type(4)));

static __device__ __forceinline__ unsigned short f2bf(float f) {
    unsigned u = __float_as_uint(f);
    unsigned r = u + 0x7FFF + ((u >> 16) & 1);   // RNE
    return (unsigned short)(r >> 16);
}

// ---------------------------------------------------------------------------
// Pre-permute W (fp32 [512][128]) into bf16 B-fragment order.
// ---------------------------------------------------------------------------
__global__ __launch_bounds__(256) void permute_w_kernel(const float* __restrict__ W,
                                                        unsigned short* __restrict__ Wp) {
    int tid = blockIdx.x * blockDim.x + threadIdx.x;  // 0..8191
    if (tid >= 16 * 8 * 64) return;
    int lane = tid & 63;
    int nt   = (tid >> 6) & 7;
    int kb4  = tid >> 9;
    int n    = nt * 16 + (lane & 15);
    int kbase = kb4 * 32 + ((lane >> 4) & 3) * 8;
    unsigned short frag[8];
#pragma unroll
    for (int j = 0; j < 8; ++j)
        frag[j] = f2bf(W[(size_t)(kbase + j) * D_OUT_N + n]);
    *(uint4*)&Wp[(size_t)tid * 8] = *(const uint4*)frag;
}

// ---------------------------------------------------------------------------
// h = x @ W via bf16 MFMA 16x16x32. Wave = 16 rows x 128 cols. No LDS.
// ALL x loads hoisted first (32 float4 in flight) -> latency hidden by ILP,
// then packed bf16 converts + MFMA. Wp is L2-resident.
// ---------------------------------------------------------------------------
__global__ __launch_bounds__(256) void mfma_gemm_kernel(const float* __restrict__ x,
                                                        const unsigned short* __restrict__ Wp,
                                                        float* __restrict__ h) {
    const int wave = threadIdx.x >> 6;
    const int lane = threadIdx.x & 63;
    const int m0   = blockIdx.x * 64 + wave * 16;
    if (m0 >= M_NODES) return;

    const int arow   = m0 + (lane & 15);
    const int rclamp = (arow < M_NODES) ? arow : (M_NODES - 1);
    const int kgrp   = lane >> 4;                  // 0..3
    const float* xrow = x + (size_t)rclamp * D_IN_K + kgrp * 8;

    // Hoist the entire row slice: 16 iterations x 2 float4 = 128 VGPRs.
    float4 xa[32];
#pragma unroll
    for (int i = 0; i < 16; ++i) {
        xa[2 * i]     = *(const float4*)(xrow + i * 32);
        xa[2 * i + 1] = *(const float4*)(xrow + i * 32 + 4);
    }

    f32x4 acc[8];
#pragma unroll
    for (int t = 0; t < 8; ++t) acc[t] = (f32x4){0.f, 0.f, 0.f, 0.f};

#pragma unroll
    for (int kb4 = 0; kb4 < 16; ++kb4) {
        const float* pf = (const float*)&xa[2 * kb4];
        union { bf16x8 v; __hip_bfloat162 h2[4]; } cv;
#pragma unroll
        for (int j = 0; j < 4; ++j)
            cv.h2[j] = __float22bfloat162_rn(make_float2(pf[2 * j], pf[2 * j + 1]));
        bf16x8 a = cv.v;
        const unsigned short* wp = Wp + ((size_t)(kb4 * 8) * 64 + lane) * 8;
#pragma unroll
        for (int nt = 0; nt < 8; ++nt) {
            bf16x8 bfr = *(const bf16x8*)(wp + (size_t)nt * 64 * 8);
            acc[nt] = __builtin_amdgcn_mfma_f32_16x16x32_bf16(a, bfr, acc[nt], 0, 0, 0);
        }
    }

    // C/D layout: col = lane&15, row = (lane>>4)*4 + r
    const int col = lane & 15;
#pragma unroll
    for (int r = 0; r < 4; ++r) {
        int rr = m0 + kgrp * 4 + r;
        if (rr < M_NODES) {
            float* hp = &h[(size_t)rr * D_OUT_N + col];
#pragma unroll
            for (int nt = 0; nt < 8; ++nt)
                hp[nt * 16] = acc[nt][r];
        }
    }
}

// ---------------------------------------------------------------------------
// CSR build
// ---------------------------------------------------------------------------
__global__ __launch_bounds__(256) void zero_kernel(int* __restrict__ counts) {
    int i = blockIdx.x * blockDim.x + threadIdx.x;
    if (i < M_NODES) counts[i] = 0;
}

__global__ __launch_bounds__(256) void hist_kernel(const int* __restrict__ dst,
                                                   int* __restrict__ counts) {
    int e = blockIdx.x * blockDim.x + threadIdx.x;
    if (e < N_EDGES) atomicAdd(&counts[dst[e]], 1);
}

__global__ __launch_bounds__(256) void scan_partial_kernel(const int* __restrict__ counts,
                                                           int* __restrict__ offsets,
                                                           int* __restrict__ partials) {
    __shared__ int wsum[4];
    const int tid  = threadIdx.x;
    const int lane = tid & 63;
    const int wid  = tid >> 6;
    const int base = blockIdx.x * 1024 + tid * 4;

    int v[4];
#pragma unroll
    for (int i = 0; i < 4; ++i) v[i] = (base + i < M_NODES) ? counts[base + i] : 0;
    int t = v[0] + v[1] + v[2] + v[3];

    int s = t;
#pragma unroll
    for (int d = 1; d < 64; d <<= 1) {
        int u = __shfl_up(s, d, 64);
        if (lane >= d) s += u;
    }
    if (lane == 63) wsum[wid] = s;
    __syncthreads();
    int wbase = 0;
#pragma unroll
    for (int w = 0; w < 4; ++w) wbase += (w < wid) ? wsum[w] : 0;

    int run = wbase + s - t;
#pragma unroll
    for (int i = 0; i < 4; ++i) {
        if (base + i < M_NODES) offsets[base + i] = run;
        run += v[i];
    }
    if (tid == 255) partials[blockIdx.x] = wbase + s;
}

__global__ __launch_bounds__(64) void scan_carry_kernel(const int* __restrict__ partials,
                                                        int* __restrict__ carries,
                                                        int* __restrict__ offsets) {
    int lane = threadIdx.x;
    int v = (lane < SCAN_NBLK) ? partials[lane] : 0;
    int s = v;
#pragma unroll
    for (int d = 1; d < 64; d <<= 1) {
        int u = __shfl_up(s, d, 64);
        if (lane >= d) s += u;
    }
    if (lane < SCAN_NBLK) carries[lane] = s - v;
    if (lane == 63) offsets[M_NODES] = s;
}

__global__ __launch_bounds__(256) void scan_add_kernel(int* __restrict__ offsets,
                                                       const int* __restrict__ carries,
                                                       int* __restrict__ cursor) {
    const int base = blockIdx.x * 1024 + threadIdx.x * 4;
    const int c = carries[blockIdx.x];
#pragma unroll
    for (int i = 0; i < 4; ++i) {
        if (base + i < M_NODES) {
            int o = offsets[base + i] + c;
            offsets[base + i] = o;
            cursor[base + i] = o;
        }
    }
}

__global__ __launch_bounds__(256) void fill_kernel(const int* __restrict__ src,
                                                   const int* __restrict__ dst,
                                                   const float* __restrict__ edge_w,
                                                   int* __restrict__ cursor,
                                                   int2* __restrict__ ep) {
    int e = blockIdx.x * blockDim.x + threadIdx.x;
    if (e >= N_EDGES) return;
    int d   = dst[e];
    int pos = atomicAdd(&cursor[d], 1);
    ep[pos] = make_int2(src[e], __float_as_int(edge_w[e]));
}

// ---------------------------------------------------------------------------
// Gather: out[i] = b + sum w_e * h[src_e]. 32 lanes/node, 2-edge unroll
// with independent accumulators for ILP.
// ---------------------------------------------------------------------------
__global__ __launch_bounds__(256) void gather_kernel(const float* __restrict__ h,
                                                     const int2* __restrict__ ep,
                                                     const int* __restrict__ offsets,
                                                     const float* __restrict__ b,
                                                     float* __restrict__ out) {
    int node = (int)((blockIdx.x * (long long)blockDim.x + threadIdx.x) >> 5);
    int lane = threadIdx.x & 31;
    if (node >= M_NODES) return;
    int beg = offsets[node];
    int end = offsets[node + 1];
    float4 a0 = *(const float4*)&b[lane * 4];
    float4 a1 = make_float4(0.f, 0.f, 0.f, 0.f);
    int j = beg;
    for (; j + 2 <= end; j += 2) {
        int2 e0 = ep[j];
        int2 e1 = ep[j + 1];
        float w0 = __int_as_float(e0.y);
        float w1 = __int_as_float(e1.y);
        float4 h0 = *(const float4*)&h[(size_t)e0.x * D_OUT_N + lane * 4];
        float4 h1 = *(const float4*)&h[(size_t)e1.x * D_OUT_N + lane * 4];
        a0.x += w0 * h0.x;  a0.y += w0 * h0.y;  a0.z += w0 * h0.z;  a0.w += w0 * h0.w;
        a1.x += w1 * h1.x;  a1.y += w1 * h1.y;  a1.z += w1 * h1.z;  a1.w += w1 * h1.w;
    }
    if (j < end) {
        int2 e0 = ep[j];
        float w0 = __int_as_float(e0.y);
        float4 h0 = *(const float4*)&h[(size_t)e0.x * D_OUT_N + lane * 4];
        a0.x += w0 * h0.x;  a0.y += w0 * h0.y;  a0.z += w0 * h0.z;  a0.w += w0 * h0.w;
    }
    a0.x += a1.x;  a0.y += a1.y;  a0.z += a1.z;  a0.w += a1.w;
    *(float4*)&out[(size_t)node * D_OUT_N + lane * 4] = a0;
}

extern "C" void kernel_launch(void* const* d_in, const int* in_sizes, int n_in,
                              void* d_out, int out_size, void* d_ws, size_t ws_size,
                              hipStream_t stream) {
    const float* x      = (const float*)d_in[0];
    const float* edge_w = (const float*)d_in[1];
    const int*   src    = (const int*)d_in[2];
    const int*   dst    = (const int*)d_in[3];
    const float* W      = (const float*)d_in[4];
    const float* b      = (const float*)d_in[5];
    float* out = (float*)d_out;

    char* wsp = (char*)d_ws;
    float* h        = (float*)wsp;       wsp += (size_t)M_NODES * D_OUT_N * 4;            // 25.6 MB
    int*   counts   = (int*)wsp;         wsp += ((size_t)M_NODES * 4 + 15) & ~15ull;
    int*   offsets  = (int*)wsp;         wsp += (((size_t)M_NODES + 1) * 4 + 15) & ~15ull;
    int*   cursor   = (int*)wsp;         wsp += ((size_t)M_NODES * 4 + 15) & ~15ull;
    int2*  ep       = (int2*)wsp;        wsp += (size_t)N_EDGES * 8;                      // 6.4 MB
    unsigned short* Wp = (unsigned short*)wsp; wsp += (size_t)16 * 8 * 64 * 8 * 2;        // 128 KB
    int*   partials = (int*)wsp;         wsp += (SCAN_NBLK * 4 + 15) & ~15ull;
    int*   carries  = (int*)wsp;         wsp += (SCAN_NBLK * 4 + 15) & ~15ull;

    permute_w_kernel<<<(16 * 8 * 64 + 255) / 256, 256, 0, stream>>>(W, Wp);
    mfma_gemm_kernel<<<(M_NODES + 63) / 64, 256, 0, stream>>>(x, Wp, h);
    zero_kernel<<<(M_NODES + 255) / 256, 256, 0, stream>>>(counts);
    hist_kernel<<<(N_EDGES + 255) / 256, 256, 0, stream>>>(dst, counts);
    scan_partial_kernel<<<SCAN_NBLK, 256, 0, stream>>>(counts, offsets, partials);
    scan_carry_kernel<<<1, 64, 0, stream>>>(partials, carries, offsets);
    scan_add_kernel<<<SCAN_NBLK, 256, 0, stream>>>(offsets, carries, cursor);
    fill_kernel<<<(N_EDGES + 255) / 256, 256, 0, stream>>>(src, dst, edge_w, cursor, ep);
    gather_kernel<<<(int)(((long long)M_NODES * 32 + 255) / 256), 256, 0, stream>>>(
        h, ep, offsets, b, out);
}

// Round 5
// 312.285 us; speedup vs baseline: 5.0484x; 1.0689x over previous
//
#include <hip/hip_runtime.h>
#include <hip/hip_bf16.h>

#define M_NODES  50000
#define D_IN_K   512
#define D_OUT_N  128
#define N_EDGES  800000
#define SCAN_NBLK 49   // ceil(50000/1024)

typedef short  bf16x8 __attribute__((ext_vector_type(8)));
typedef float  f32x4  __attribute__((ext_vector_type(4)));

static __device__ __forceinline__ unsigned short f2bf(float f) {
    unsigned u = __float_as_uint(f);
    unsigned r = u + 0x7FFF + ((u >> 16) & 1);   // RNE
    return (unsigned short)(r >> 16);
}
static __device__ __forceinline__ float bflo(unsigned q) { return __uint_as_float(q << 16); }
static __device__ __forceinline__ float bfhi(unsigned q) { return __uint_as_float(q & 0xFFFF0000u); }

union WFrag { uint4 u; bf16x8 v; };

// ---------------------------------------------------------------------------
// Setup (fused): blocks [0,32) permute W into bf16 B-fragment order;
// blocks [32,228) zero the counts array.
// ---------------------------------------------------------------------------
__global__ __launch_bounds__(256) void setup_kernel(const float* __restrict__ W,
                                                    unsigned short* __restrict__ Wp,
                                                    int* __restrict__ counts) {
    if (blockIdx.x < 32) {
        int tid = blockIdx.x * 256 + threadIdx.x;  // 0..8191
        int lane = tid & 63;
        int nt   = (tid >> 6) & 7;
        int kb4  = tid >> 9;
        int n    = nt * 16 + (lane & 15);
        int kbase = kb4 * 32 + ((lane >> 4) & 3) * 8;
        unsigned short frag[8];
#pragma unroll
        for (int j = 0; j < 8; ++j)
            frag[j] = f2bf(W[(size_t)(kbase + j) * D_OUT_N + n]);
        *(uint4*)&Wp[(size_t)tid * 8] = *(const uint4*)frag;
    } else {
        int i = (blockIdx.x - 32) * 256 + threadIdx.x;
        if (i < M_NODES) counts[i] = 0;
    }
}

// ---------------------------------------------------------------------------
// h(bf16) = x @ W via bf16 MFMA 16x16x32. Block = 128 thr = 2 waves.
// Wave = 32 rows (2 m-frags) x 128 cols (8 n-tiles): 16 MFMA per 8 B-frag
// loads. Explicit 1-deep software pipeline: prefetch next kb4's x (HBM) and
// Wp (L2) while MFMAing current. No LDS.
// ---------------------------------------------------------------------------
__global__ __launch_bounds__(128) void mfma_gemm_kernel(const float* __restrict__ x,
                                                        const unsigned short* __restrict__ Wp,
                                                        unsigned short* __restrict__ h) {
    const int wave = threadIdx.x >> 6;        // 0..1
    const int lane = threadIdx.x & 63;
    const int m0   = blockIdx.x * 64 + wave * 32;
    const int mrow = lane & 15;
    const int kgrp = lane >> 4;               // 0..3

    const int r0 = m0 + mrow;
    const int r1 = m0 + 16 + mrow;
    const float* xr0 = x + (size_t)((r0 < M_NODES) ? r0 : M_NODES - 1) * D_IN_K + kgrp * 8;
    const float* xr1 = x + (size_t)((r1 < M_NODES) ? r1 : M_NODES - 1) * D_IN_K + kgrp * 8;
    const unsigned short* wpl = Wp + (size_t)lane * 8;  // + kb4*4096 + nt*512

    f32x4 acc[2][8];
#pragma unroll
    for (int f = 0; f < 2; ++f)
#pragma unroll
        for (int t = 0; t < 8; ++t) acc[f][t] = (f32x4){0.f, 0.f, 0.f, 0.f};

    // --- pipeline prologue: load kb4=0 ---
    float4 xa00 = *(const float4*)(xr0);
    float4 xa01 = *(const float4*)(xr0 + 4);
    float4 xa10 = *(const float4*)(xr1);
    float4 xa11 = *(const float4*)(xr1 + 4);
    WFrag wf[8];
#pragma unroll
    for (int nt = 0; nt < 8; ++nt)
        wf[nt].u = *(const uint4*)(wpl + (size_t)nt * 512);

#pragma unroll
    for (int kb4 = 0; kb4 < 16; ++kb4) {
        float4 xb00, xb01, xb10, xb11;
        WFrag wg[8];
        if (kb4 < 15) {
            const float* p0 = xr0 + (kb4 + 1) * 32;
            const float* p1 = xr1 + (kb4 + 1) * 32;
            xb00 = *(const float4*)p0;  xb01 = *(const float4*)(p0 + 4);
            xb10 = *(const float4*)p1;  xb11 = *(const float4*)(p1 + 4);
            const unsigned short* wq = wpl + (size_t)(kb4 + 1) * 4096;
#pragma unroll
            for (int nt = 0; nt < 8; ++nt)
                wg[nt].u = *(const uint4*)(wq + (size_t)nt * 512);
        }

        union { bf16x8 v; __hip_bfloat162 h2[4]; } c0, c1;
        c0.h2[0] = __float22bfloat162_rn(make_float2(xa00.x, xa00.y));
        c0.h2[1] = __float22bfloat162_rn(make_float2(xa00.z, xa00.w));
        c0.h2[2] = __float22bfloat162_rn(make_float2(xa01.x, xa01.y));
        c0.h2[3] = __float22bfloat162_rn(make_float2(xa01.z, xa01.w));
        c1.h2[0] = __float22bfloat162_rn(make_float2(xa10.x, xa10.y));
        c1.h2[1] = __float22bfloat162_rn(make_float2(xa10.z, xa10.w));
        c1.h2[2] = __float22bfloat162_rn(make_float2(xa11.x, xa11.y));
        c1.h2[3] = __float22bfloat162_rn(make_float2(xa11.z, xa11.w));
        bf16x8 a0 = c0.v, a1 = c1.v;

#pragma unroll
        for (int nt = 0; nt < 8; ++nt) {
            acc[0][nt] = __builtin_amdgcn_mfma_f32_16x16x32_bf16(a0, wf[nt].v, acc[0][nt], 0, 0, 0);
            acc[1][nt] = __builtin_amdgcn_mfma_f32_16x16x32_bf16(a1, wf[nt].v, acc[1][nt], 0, 0, 0);
        }

        if (kb4 < 15) {
            xa00 = xb00;  xa01 = xb01;  xa10 = xb10;  xa11 = xb11;
#pragma unroll
            for (int nt = 0; nt < 8; ++nt) wf[nt] = wg[nt];
        }
    }

    // C/D layout: col = lane&15, row = kgrp*4 + r (per 16-row m-frag)
#pragma unroll
    for (int f = 0; f < 2; ++f)
#pragma unroll
        for (int r = 0; r < 4; ++r) {
            int rr = m0 + f * 16 + kgrp * 4 + r;
            if (rr < M_NODES) {
                unsigned short* hp = h + (size_t)rr * D_OUT_N + mrow;
#pragma unroll
                for (int nt = 0; nt < 8; ++nt)
                    hp[nt * 16] = f2bf(acc[f][nt][r]);
            }
        }
}

// ---------------------------------------------------------------------------
// CSR build
// ---------------------------------------------------------------------------
__global__ __launch_bounds__(256) void hist_kernel(const int* __restrict__ dst,
                                                   int* __restrict__ counts) {
    int e = blockIdx.x * blockDim.x + threadIdx.x;
    if (e < N_EDGES) atomicAdd(&counts[dst[e]], 1);
}

__global__ __launch_bounds__(256) void scan_partial_kernel(const int* __restrict__ counts,
                                                           int* __restrict__ offsets,
                                                           int* __restrict__ partials) {
    __shared__ int wsum[4];
    const int tid  = threadIdx.x;
    const int lane = tid & 63;
    const int wid  = tid >> 6;
    const int base = blockIdx.x * 1024 + tid * 4;

    int v[4];
#pragma unroll
    for (int i = 0; i < 4; ++i) v[i] = (base + i < M_NODES) ? counts[base + i] : 0;
    int t = v[0] + v[1] + v[2] + v[3];

    int s = t;
#pragma unroll
    for (int d = 1; d < 64; d <<= 1) {
        int u = __shfl_up(s, d, 64);
        if (lane >= d) s += u;
    }
    if (lane == 63) wsum[wid] = s;
    __syncthreads();
    int wbase = 0;
#pragma unroll
    for (int w = 0; w < 4; ++w) wbase += (w < wid) ? wsum[w] : 0;

    int run = wbase + s - t;
#pragma unroll
    for (int i = 0; i < 4; ++i) {
        if (base + i < M_NODES) offsets[base + i] = run;
        run += v[i];
    }
    if (tid == 255) partials[blockIdx.x] = wbase + s;
}

__global__ __launch_bounds__(64) void scan_carry_kernel(const int* __restrict__ partials,
                                                        int* __restrict__ carries,
                                                        int* __restrict__ offsets) {
    int lane = threadIdx.x;
    int v = (lane < SCAN_NBLK) ? partials[lane] : 0;
    int s = v;
#pragma unroll
    for (int d = 1; d < 64; d <<= 1) {
        int u = __shfl_up(s, d, 64);
        if (lane >= d) s += u;
    }
    if (lane < SCAN_NBLK) carries[lane] = s - v;
    if (lane == 63) offsets[M_NODES] = s;
}

__global__ __launch_bounds__(256) void scan_add_kernel(int* __restrict__ offsets,
                                                       const int* __restrict__ carries,
                                                       int* __restrict__ cursor) {
    const int base = blockIdx.x * 1024 + threadIdx.x * 4;
    const int c = carries[blockIdx.x];
#pragma unroll
    for (int i = 0; i < 4; ++i) {
        if (base + i < M_NODES) {
            int o = offsets[base + i] + c;
            offsets[base + i] = o;
            cursor[base + i] = o;
        }
    }
}

__global__ __launch_bounds__(256) void fill_kernel(const int* __restrict__ src,
                                                   const int* __restrict__ dst,
                                                   const float* __restrict__ edge_w,
                                                   int* __restrict__ cursor,
                                                   int2* __restrict__ ep) {
    int e = blockIdx.x * blockDim.x + threadIdx.x;
    if (e >= N_EDGES) return;
    int d   = dst[e];
    int pos = atomicAdd(&cursor[d], 1);
    ep[pos] = make_int2(src[e], __float_as_int(edge_w[e]));
}

// ---------------------------------------------------------------------------
// Gather: out[i] = b + sum w_e * h_bf16[src_e]. 32 lanes/node (4 cols each),
// 4-edge unroll with 4 independent accumulators (4 L3 gathers in flight).
// ---------------------------------------------------------------------------
__global__ __launch_bounds__(256) void gather_kernel(const unsigned short* __restrict__ h,
                                                     const int2* __restrict__ ep,
                                                     const int* __restrict__ offsets,
                                                     const float* __restrict__ b,
                                                     float* __restrict__ out) {
    int node = (int)((blockIdx.x * (long long)blockDim.x + threadIdx.x) >> 5);
    int lane = threadIdx.x & 31;
    if (node >= M_NODES) return;
    int beg = offsets[node];
    int end = offsets[node + 1];

    float4 a0 = *(const float4*)&b[lane * 4];
    float4 a1 = make_float4(0.f, 0.f, 0.f, 0.f);
    float4 a2 = make_float4(0.f, 0.f, 0.f, 0.f);
    float4 a3 = make_float4(0.f, 0.f, 0.f, 0.f);

    int j = beg;
    for (; j + 4 <= end; j += 4) {
        int2 e0 = ep[j], e1 = ep[j + 1], e2 = ep[j + 2], e3 = ep[j + 3];
        uint2 q0 = *(const uint2*)(h + (size_t)e0.x * D_OUT_N + lane * 4);
        uint2 q1 = *(const uint2*)(h + (size_t)e1.x * D_OUT_N + lane * 4);
        uint2 q2 = *(const uint2*)(h + (size_t)e2.x * D_OUT_N + lane * 4);
        uint2 q3 = *(const uint2*)(h + (size_t)e3.x * D_OUT_N + lane * 4);
        float w0 = __int_as_float(e0.y), w1 = __int_as_float(e1.y);
        float w2 = __int_as_float(e2.y), w3 = __int_as_float(e3.y);
        a0.x += w0 * bflo(q0.x);  a0.y += w0 * bfhi(q0.x);
        a0.z += w0 * bflo(q0.y);  a0.w += w0 * bfhi(q0.y);
        a1.x += w1 * bflo(q1.x);  a1.y += w1 * bfhi(q1.x);
        a1.z += w1 * bflo(q1.y);  a1.w += w1 * bfhi(q1.y);
        a2.x += w2 * bflo(q2.x);  a2.y += w2 * bfhi(q2.x);
        a2.z += w2 * bflo(q2.y);  a2.w += w2 * bfhi(q2.y);
        a3.x += w3 * bflo(q3.x);  a3.y += w3 * bfhi(q3.x);
        a3.z += w3 * bflo(q3.y);  a3.w += w3 * bfhi(q3.y);
    }
    for (; j < end; ++j) {
        int2 e0 = ep[j];
        float w0 = __int_as_float(e0.y);
        uint2 q0 = *(const uint2*)(h + (size_t)e0.x * D_OUT_N + lane * 4);
        a0.x += w0 * bflo(q0.x);  a0.y += w0 * bfhi(q0.x);
        a0.z += w0 * bflo(q0.y);  a0.w += w0 * bfhi(q0.y);
    }
    a0.x += a1.x + a2.x + a3.x;
    a0.y += a1.y + a2.y + a3.y;
    a0.z += a1.z + a2.z + a3.z;
    a0.w += a1.w + a2.w + a3.w;
    *(float4*)&out[(size_t)node * D_OUT_N + lane * 4] = a0;
}

extern "C" void kernel_launch(void* const* d_in, const int* in_sizes, int n_in,
                              void* d_out, int out_size, void* d_ws, size_t ws_size,
                              hipStream_t stream) {
    const float* x      = (const float*)d_in[0];
    const float* edge_w = (const float*)d_in[1];
    const int*   src    = (const int*)d_in[2];
    const int*   dst    = (const int*)d_in[3];
    const float* W      = (const float*)d_in[4];
    const float* b      = (const float*)d_in[5];
    float* out = (float*)d_out;

    char* wsp = (char*)d_ws;
    unsigned short* h = (unsigned short*)wsp;  wsp += (size_t)M_NODES * D_OUT_N * 2;      // 12.8 MB
    int*   counts   = (int*)wsp;         wsp += ((size_t)M_NODES * 4 + 15) & ~15ull;
    int*   offsets  = (int*)wsp;         wsp += (((size_t)M_NODES + 1) * 4 + 15) & ~15ull;
    int*   cursor   = (int*)wsp;         wsp += ((size_t)M_NODES * 4 + 15) & ~15ull;
    int2*  ep       = (int2*)wsp;        wsp += (size_t)N_EDGES * 8;                      // 6.4 MB
    unsigned short* Wp = (unsigned short*)wsp; wsp += (size_t)16 * 8 * 64 * 8 * 2;        // 128 KB
    int*   partials = (int*)wsp;         wsp += (SCAN_NBLK * 4 + 15) & ~15ull;
    int*   carries  = (int*)wsp;         wsp += (SCAN_NBLK * 4 + 15) & ~15ull;

    setup_kernel<<<32 + (M_NODES + 255) / 256, 256, 0, stream>>>(W, Wp, counts);
    mfma_gemm_kernel<<<(M_NODES + 63) / 64, 128, 0, stream>>>(x, Wp, h);
    hist_kernel<<<(N_EDGES + 255) / 256, 256, 0, stream>>>(dst, counts);
    scan_partial_kernel<<<SCAN_NBLK, 256, 0, stream>>>(counts, offsets, partials);
    scan_carry_kernel<<<1, 64, 0, stream>>>(partials, carries, offsets);
    scan_add_kernel<<<SCAN_NBLK, 256, 0, stream>>>(offsets, carries, cursor);
    fill_kernel<<<(N_EDGES + 255) / 256, 256, 0, stream>>>(src, dst, edge_w, cursor, ep);
    gather_kernel<<<(int)(((long long)M_NODES * 32 + 255) / 256), 256, 0, stream>>>(
        h, ep, offsets, b, out);
}

// Round 6
// 297.259 us; speedup vs baseline: 5.3036x; 1.0506x over previous
//
#include <hip/hip_runtime.h>
#include <hip/hip_bf16.h>

#define M_NODES  50000
#define D_IN_K   512
#define D_OUT_N  128
#define N_EDGES  800000
#define SCAN_NBLK 49   // ceil(50000/1024)

typedef short  bf16x8 __attribute__((ext_vector_type(8)));
typedef float  f32x4  __attribute__((ext_vector_type(4)));

static __device__ __forceinline__ unsigned short f2bf(float f) {
    unsigned u = __float_as_uint(f);
    unsigned r = u + 0x7FFF + ((u >> 16) & 1);   // RNE
    return (unsigned short)(r >> 16);
}
static __device__ __forceinline__ float bflo(unsigned q) { return __uint_as_float(q << 16); }
static __device__ __forceinline__ float bfhi(unsigned q) { return __uint_as_float(q & 0xFFFF0000u); }

// ---------------------------------------------------------------------------
// Setup (fused): blocks [0,32) permute W into bf16 B-fragment order
// Wp[(kb4*8 + nt)*64 + lane] (uint4 frags); blocks [32,...) zero counts.
// ---------------------------------------------------------------------------
__global__ __launch_bounds__(256) void setup_kernel(const float* __restrict__ W,
                                                    unsigned short* __restrict__ Wp,
                                                    int* __restrict__ counts) {
    if (blockIdx.x < 32) {
        int tid = blockIdx.x * 256 + threadIdx.x;  // 0..8191
        int lane = tid & 63;
        int nt   = (tid >> 6) & 7;
        int kb4  = tid >> 9;
        int n    = nt * 16 + (lane & 15);
        int kbase = kb4 * 32 + ((lane >> 4) & 3) * 8;
        unsigned short frag[8];
#pragma unroll
        for (int j = 0; j < 8; ++j)
            frag[j] = f2bf(W[(size_t)(kbase + j) * D_OUT_N + n]);
        *(uint4*)&Wp[(size_t)tid * 8] = *(const uint4*)frag;
    } else {
        int i = (blockIdx.x - 32) * 256 + threadIdx.x;
        if (i < M_NODES) counts[i] = 0;
    }
}

// ---------------------------------------------------------------------------
// h(bf16) = x @ W, bf16 MFMA 16x16x32. Block = 256 thr (4 waves), BM = 128
// (wave = 32 rows x 128 cols). B-frags staged through 64 KB LDS (half of K,
// restaged once) so vmcnt carries ONLY x loads -> x pipeline stays in flight.
// ds_read_b128 of W frags is conflict-free (contiguous 1 KB per frag).
// ---------------------------------------------------------------------------
__global__ __launch_bounds__(256, 2) void mfma_gemm_kernel(const float* __restrict__ x,
                                                           const uint4* __restrict__ Wp4,
                                                           unsigned short* __restrict__ h) {
    __shared__ uint4 wlds[4096];              // 64 KB: [kb 8][nt 8][lane 64]

    const int wave = threadIdx.x >> 6;        // 0..3
    const int lane = threadIdx.x & 63;
    const int m0   = blockIdx.x * 128 + wave * 32;
    const int mrow = lane & 15;
    const int kgrp = lane >> 4;               // 0..3

    const int r0 = m0 + mrow;
    const int r1 = m0 + 16 + mrow;
    const float* xr0 = x + (size_t)((r0 < M_NODES) ? r0 : M_NODES - 1) * D_IN_K + kgrp * 8;
    const float* xr1 = x + (size_t)((r1 < M_NODES) ? r1 : M_NODES - 1) * D_IN_K + kgrp * 8;

    f32x4 acc[2][8];
#pragma unroll
    for (int f = 0; f < 2; ++f)
#pragma unroll
        for (int t = 0; t < 8; ++t) acc[f][t] = (f32x4){0.f, 0.f, 0.f, 0.f};

    for (int half = 0; half < 2; ++half) {
        __syncthreads();                      // protect prior half's LDS reads
#pragma unroll
        for (int i = 0; i < 16; ++i)
            wlds[threadIdx.x + i * 256] = Wp4[half * 4096 + threadIdx.x + i * 256];
        __syncthreads();

        const float* px0 = xr0 + half * 256;  // 8 kb4 * 32 floats
        const float* px1 = xr1 + half * 256;

        float4 a00 = *(const float4*)(px0);
        float4 a01 = *(const float4*)(px0 + 4);
        float4 a10 = *(const float4*)(px1);
        float4 a11 = *(const float4*)(px1 + 4);

#pragma unroll
        for (int kb = 0; kb < 8; ++kb) {
            float4 n00, n01, n10, n11;
            if (kb < 7) {
                n00 = *(const float4*)(px0 + (kb + 1) * 32);
                n01 = *(const float4*)(px0 + (kb + 1) * 32 + 4);
                n10 = *(const float4*)(px1 + (kb + 1) * 32);
                n11 = *(const float4*)(px1 + (kb + 1) * 32 + 4);
            }

            union { bf16x8 v; __hip_bfloat162 h2[4]; } c0, c1;
            c0.h2[0] = __float22bfloat162_rn(make_float2(a00.x, a00.y));
            c0.h2[1] = __float22bfloat162_rn(make_float2(a00.z, a00.w));
            c0.h2[2] = __float22bfloat162_rn(make_float2(a01.x, a01.y));
            c0.h2[3] = __float22bfloat162_rn(make_float2(a01.z, a01.w));
            c1.h2[0] = __float22bfloat162_rn(make_float2(a10.x, a10.y));
            c1.h2[1] = __float22bfloat162_rn(make_float2(a10.z, a10.w));
            c1.h2[2] = __float22bfloat162_rn(make_float2(a11.x, a11.y));
            c1.h2[3] = __float22bfloat162_rn(make_float2(a11.z, a11.w));
            bf16x8 a0 = c0.v, a1 = c1.v;

#pragma unroll
            for (int nt = 0; nt < 8; ++nt) {
                union { uint4 u; bf16x8 v; } wb;
                wb.u = wlds[(kb * 8 + nt) * 64 + lane];
                acc[0][nt] = __builtin_amdgcn_mfma_f32_16x16x32_bf16(a0, wb.v, acc[0][nt], 0, 0, 0);
                acc[1][nt] = __builtin_amdgcn_mfma_f32_16x16x32_bf16(a1, wb.v, acc[1][nt], 0, 0, 0);
            }

            if (kb < 7) { a00 = n00; a01 = n01; a10 = n10; a11 = n11; }
        }
    }

    // C/D layout: col = lane&15, row = kgrp*4 + r (per 16-row m-frag)
#pragma unroll
    for (int f = 0; f < 2; ++f)
#pragma unroll
        for (int r = 0; r < 4; ++r) {
            int rr = m0 + f * 16 + kgrp * 4 + r;
            if (rr < M_NODES) {
                unsigned short* hp = h + (size_t)rr * D_OUT_N + mrow;
#pragma unroll
                for (int nt = 0; nt < 8; ++nt)
                    hp[nt * 16] = f2bf(acc[f][nt][r]);
            }
        }
}

// ---------------------------------------------------------------------------
// CSR build
// ---------------------------------------------------------------------------
__global__ __launch_bounds__(256) void hist_kernel(const int* __restrict__ dst,
                                                   int* __restrict__ counts) {
    int e = blockIdx.x * blockDim.x + threadIdx.x;
    if (e < N_EDGES) atomicAdd(&counts[dst[e]], 1);
}

__global__ __launch_bounds__(256) void scan_partial_kernel(const int* __restrict__ counts,
                                                           int* __restrict__ offsets,
                                                           int* __restrict__ partials) {
    __shared__ int wsum[4];
    const int tid  = threadIdx.x;
    const int lane = tid & 63;
    const int wid  = tid >> 6;
    const int base = blockIdx.x * 1024 + tid * 4;

    int v[4];
#pragma unroll
    for (int i = 0; i < 4; ++i) v[i] = (base + i < M_NODES) ? counts[base + i] : 0;
    int t = v[0] + v[1] + v[2] + v[3];

    int s = t;
#pragma unroll
    for (int d = 1; d < 64; d <<= 1) {
        int u = __shfl_up(s, d, 64);
        if (lane >= d) s += u;
    }
    if (lane == 63) wsum[wid] = s;
    __syncthreads();
    int wbase = 0;
#pragma unroll
    for (int w = 0; w < 4; ++w) wbase += (w < wid) ? wsum[w] : 0;

    int run = wbase + s - t;
#pragma unroll
    for (int i = 0; i < 4; ++i) {
        if (base + i < M_NODES) offsets[base + i] = run;
        run += v[i];
    }
    if (tid == 255) partials[blockIdx.x] = wbase + s;
}

__global__ __launch_bounds__(64) void scan_carry_kernel(const int* __restrict__ partials,
                                                        int* __restrict__ carries,
                                                        int* __restrict__ offsets) {
    int lane = threadIdx.x;
    int v = (lane < SCAN_NBLK) ? partials[lane] : 0;
    int s = v;
#pragma unroll
    for (int d = 1; d < 64; d <<= 1) {
        int u = __shfl_up(s, d, 64);
        if (lane >= d) s += u;
    }
    if (lane < SCAN_NBLK) carries[lane] = s - v;
    if (lane == 63) offsets[M_NODES] = s;
}

__global__ __launch_bounds__(256) void scan_add_kernel(int* __restrict__ offsets,
                                                       const int* __restrict__ carries,
                                                       int* __restrict__ cursor) {
    const int base = blockIdx.x * 1024 + threadIdx.x * 4;
    const int c = carries[blockIdx.x];
#pragma unroll
    for (int i = 0; i < 4; ++i) {
        if (base + i < M_NODES) {
            int o = offsets[base + i] + c;
            offsets[base + i] = o;
            cursor[base + i] = o;
        }
    }
}

__global__ __launch_bounds__(256) void fill_kernel(const int* __restrict__ src,
                                                   const int* __restrict__ dst,
                                                   const float* __restrict__ edge_w,
                                                   int* __restrict__ cursor,
                                                   int2* __restrict__ ep) {
    int e = blockIdx.x * blockDim.x + threadIdx.x;
    if (e >= N_EDGES) return;
    int d   = dst[e];
    int pos = atomicAdd(&cursor[d], 1);
    ep[pos] = make_int2(src[e], __float_as_int(edge_w[e]));
}

// ---------------------------------------------------------------------------
// Gather: out[i] = b + sum w_e * h_bf16[src_e]. 16 lanes/node (8 cols each,
// one uint4 per edge), 4-edge unroll with independent accumulators:
// 4 x 16 B outstanding per lane.
// ---------------------------------------------------------------------------
__global__ __launch_bounds__(256) void gather_kernel(const unsigned short* __restrict__ h,
                                                     const int2* __restrict__ ep,
                                                     const int* __restrict__ offsets,
                                                     const float* __restrict__ b,
                                                     float* __restrict__ out) {
    int t    = blockIdx.x * blockDim.x + threadIdx.x;
    int node = t >> 4;
    int lane = t & 15;
    if (node >= M_NODES) return;
    int beg = offsets[node];
    int end = offsets[node + 1];

    float4 b0 = *(const float4*)&b[lane * 8];
    float4 b1 = *(const float4*)&b[lane * 8 + 4];
    float a[4][8];
#pragma unroll
    for (int u = 0; u < 4; ++u)
#pragma unroll
        for (int c = 0; c < 8; ++c) a[u][c] = 0.f;

    int j = beg;
    for (; j + 4 <= end; j += 4) {
        int2 e0 = ep[j], e1 = ep[j + 1], e2 = ep[j + 2], e3 = ep[j + 3];
        uint4 q0 = *(const uint4*)(h + (size_t)e0.x * D_OUT_N + lane * 8);
        uint4 q1 = *(const uint4*)(h + (size_t)e1.x * D_OUT_N + lane * 8);
        uint4 q2 = *(const uint4*)(h + (size_t)e2.x * D_OUT_N + lane * 8);
        uint4 q3 = *(const uint4*)(h + (size_t)e3.x * D_OUT_N + lane * 8);
        float w0 = __int_as_float(e0.y), w1 = __int_as_float(e1.y);
        float w2 = __int_as_float(e2.y), w3 = __int_as_float(e3.y);
        a[0][0] += w0 * bflo(q0.x);  a[0][1] += w0 * bfhi(q0.x);
        a[0][2] += w0 * bflo(q0.y);  a[0][3] += w0 * bfhi(q0.y);
        a[0][4] += w0 * bflo(q0.z);  a[0][5] += w0 * bfhi(q0.z);
        a[0][6] += w0 * bflo(q0.w);  a[0][7] += w0 * bfhi(q0.w);
        a[1][0] += w1 * bflo(q1.x);  a[1][1] += w1 * bfhi(q1.x);
        a[1][2] += w1 * bflo(q1.y);  a[1][3] += w1 * bfhi(q1.y);
        a[1][4] += w1 * bflo(q1.z);  a[1][5] += w1 * bfhi(q1.z);
        a[1][6] += w1 * bflo(q1.w);  a[1][7] += w1 * bfhi(q1.w);
        a[2][0] += w2 * bflo(q2.x);  a[2][1] += w2 * bfhi(q2.x);
        a[2][2] += w2 * bflo(q2.y);  a[2][3] += w2 * bfhi(q2.y);
        a[2][4] += w2 * bflo(q2.z);  a[2][5] += w2 * bfhi(q2.z);
        a[2][6] += w2 * bflo(q2.w);  a[2][7] += w2 * bfhi(q2.w);
        a[3][0] += w3 * bflo(q3.x);  a[3][1] += w3 * bfhi(q3.x);
        a[3][2] += w3 * bflo(q3.y);  a[3][3] += w3 * bfhi(q3.y);
        a[3][4] += w3 * bflo(q3.z);  a[3][5] += w3 * bfhi(q3.z);
        a[3][6] += w3 * bflo(q3.w);  a[3][7] += w3 * bfhi(q3.w);
    }
    for (; j < end; ++j) {
        int2 e0 = ep[j];
        float w0 = __int_as_float(e0.y);
        uint4 q0 = *(const uint4*)(h + (size_t)e0.x * D_OUT_N + lane * 8);
        a[0][0] += w0 * bflo(q0.x);  a[0][1] += w0 * bfhi(q0.x);
        a[0][2] += w0 * bflo(q0.y);  a[0][3] += w0 * bfhi(q0.y);
        a[0][4] += w0 * bflo(q0.z);  a[0][5] += w0 * bfhi(q0.z);
        a[0][6] += w0 * bflo(q0.w);  a[0][7] += w0 * bfhi(q0.w);
    }

    float4 o0 = make_float4(b0.x + a[0][0] + a[1][0] + a[2][0] + a[3][0],
                            b0.y + a[0][1] + a[1][1] + a[2][1] + a[3][1],
                            b0.z + a[0][2] + a[1][2] + a[2][2] + a[3][2],
                            b0.w + a[0][3] + a[1][3] + a[2][3] + a[3][3]);
    float4 o1 = make_float4(b1.x + a[0][4] + a[1][4] + a[2][4] + a[3][4],
                            b1.y + a[0][5] + a[1][5] + a[2][5] + a[3][5],
                            b1.z + a[0][6] + a[1][6] + a[2][6] + a[3][6],
                            b1.w + a[0][7] + a[1][7] + a[2][7] + a[3][7]);
    float* op = &out[(size_t)node * D_OUT_N + lane * 8];
    *(float4*)op = o0;
    *(float4*)(op + 4) = o1;
}

extern "C" void kernel_launch(void* const* d_in, const int* in_sizes, int n_in,
                              void* d_out, int out_size, void* d_ws, size_t ws_size,
                              hipStream_t stream) {
    const float* x      = (const float*)d_in[0];
    const float* edge_w = (const float*)d_in[1];
    const int*   src    = (const int*)d_in[2];
    const int*   dst    = (const int*)d_in[3];
    const float* W      = (const float*)d_in[4];
    const float* b      = (const float*)d_in[5];
    float* out = (float*)d_out;

    char* wsp = (char*)d_ws;
    unsigned short* h = (unsigned short*)wsp;  wsp += (size_t)M_NODES * D_OUT_N * 2;      // 12.8 MB
    int*   counts   = (int*)wsp;         wsp += ((size_t)M_NODES * 4 + 15) & ~15ull;
    int*   offsets  = (int*)wsp;         wsp += (((size_t)M_NODES + 1) * 4 + 15) & ~15ull;
    int*   cursor   = (int*)wsp;         wsp += ((size_t)M_NODES * 4 + 15) & ~15ull;
    int2*  ep       = (int2*)wsp;        wsp += (size_t)N_EDGES * 8;                      // 6.4 MB
    unsigned short* Wp = (unsigned short*)wsp; wsp += (size_t)16 * 8 * 64 * 8 * 2;        // 128 KB
    int*   partials = (int*)wsp;         wsp += (SCAN_NBLK * 4 + 15) & ~15ull;
    int*   carries  = (int*)wsp;         wsp += (SCAN_NBLK * 4 + 15) & ~15ull;

    setup_kernel<<<32 + (M_NODES + 255) / 256, 256, 0, stream>>>(W, Wp, counts);
    mfma_gemm_kernel<<<(M_NODES + 127) / 128, 256, 0, stream>>>(x, (const uint4*)Wp, h);
    hist_kernel<<<(N_EDGES + 255) / 256, 256, 0, stream>>>(dst, counts);
    scan_partial_kernel<<<SCAN_NBLK, 256, 0, stream>>>(counts, offsets, partials);
    scan_carry_kernel<<<1, 64, 0, stream>>>(partials, carries, offsets);
    scan_add_kernel<<<SCAN_NBLK, 256, 0, stream>>>(offsets, carries, cursor);
    fill_kernel<<<(N_EDGES + 255) / 256, 256, 0, stream>>>(src, dst, edge_w, cursor, ep);
    gather_kernel<<<(int)(((long long)M_NODES * 16 + 255) / 256), 256, 0, stream>>>(
        h, ep, offsets, b, out);
}

// Round 7
// 291.904 us; speedup vs baseline: 5.4009x; 1.0183x over previous
//
#include <hip/hip_runtime.h>
#include <hip/hip_bf16.h>

#define M_NODES  50000
#define D_IN_K   512
#define D_OUT_N  128
#define N_EDGES  800000
#define SCAN_NBLK 49   // ceil(50000/1024)
#define PAD 16         // one counter per 64B line

typedef short  bf16x8 __attribute__((ext_vector_type(8)));
typedef float  f32x4  __attribute__((ext_vector_type(4)));

static __device__ __forceinline__ unsigned short f2bf(float f) {
    unsigned u = __float_as_uint(f);
    unsigned r = u + 0x7FFF + ((u >> 16) & 1);   // RNE
    return (unsigned short)(r >> 16);
}
static __device__ __forceinline__ float bflo(unsigned q) { return __uint_as_float(q << 16); }
static __device__ __forceinline__ float bfhi(unsigned q) { return __uint_as_float(q & 0xFFFF0000u); }

// ---------------------------------------------------------------------------
// Permute W (fp32 [512][128]) into bf16 B-fragment order (uint4 frags).
// ---------------------------------------------------------------------------
__global__ __launch_bounds__(256) void permw_kernel(const float* __restrict__ W,
                                                    unsigned short* __restrict__ Wp) {
    int tid = blockIdx.x * 256 + threadIdx.x;  // 0..8191
    int lane = tid & 63;
    int nt   = (tid >> 6) & 7;
    int kb4  = tid >> 9;
    int n    = nt * 16 + (lane & 15);
    int kbase = kb4 * 32 + ((lane >> 4) & 3) * 8;
    unsigned short frag[8];
#pragma unroll
    for (int j = 0; j < 8; ++j)
        frag[j] = f2bf(W[(size_t)(kbase + j) * D_OUT_N + n]);
    *(uint4*)&Wp[(size_t)tid * 8] = *(const uint4*)frag;
}

// ---------------------------------------------------------------------------
// h(bf16) = x @ W (bf16 MFMA 16x16x32), B-frags staged via 64 KB LDS so vmcnt
// carries only x loads. Tail: fused histogram of dst (padded counters) —
// overlaps with other blocks' GEMM phase.
// ---------------------------------------------------------------------------
__global__ __launch_bounds__(256, 2) void mfma_gemm_hist_kernel(const float* __restrict__ x,
                                                                const uint4* __restrict__ Wp4,
                                                                unsigned short* __restrict__ h,
                                                                const int* __restrict__ dst,
                                                                int* __restrict__ counts) {
    __shared__ uint4 wlds[4096];              // 64 KB: [kb 8][nt 8][lane 64]

    const int wave = threadIdx.x >> 6;        // 0..3
    const int lane = threadIdx.x & 63;
    const int m0   = blockIdx.x * 128 + wave * 32;
    const int mrow = lane & 15;
    const int kgrp = lane >> 4;               // 0..3

    const int r0 = m0 + mrow;
    const int r1 = m0 + 16 + mrow;
    const float* xr0 = x + (size_t)((r0 < M_NODES) ? r0 : M_NODES - 1) * D_IN_K + kgrp * 8;
    const float* xr1 = x + (size_t)((r1 < M_NODES) ? r1 : M_NODES - 1) * D_IN_K + kgrp * 8;

    f32x4 acc[2][8];
#pragma unroll
    for (int f = 0; f < 2; ++f)
#pragma unroll
        for (int t = 0; t < 8; ++t) acc[f][t] = (f32x4){0.f, 0.f, 0.f, 0.f};

    for (int half = 0; half < 2; ++half) {
        __syncthreads();
#pragma unroll
        for (int i = 0; i < 16; ++i)
            wlds[threadIdx.x + i * 256] = Wp4[half * 4096 + threadIdx.x + i * 256];
        __syncthreads();

        const float* px0 = xr0 + half * 256;
        const float* px1 = xr1 + half * 256;

        float4 a00 = *(const float4*)(px0);
        float4 a01 = *(const float4*)(px0 + 4);
        float4 a10 = *(const float4*)(px1);
        float4 a11 = *(const float4*)(px1 + 4);

#pragma unroll
        for (int kb = 0; kb < 8; ++kb) {
            float4 n00, n01, n10, n11;
            if (kb < 7) {
                n00 = *(const float4*)(px0 + (kb + 1) * 32);
                n01 = *(const float4*)(px0 + (kb + 1) * 32 + 4);
                n10 = *(const float4*)(px1 + (kb + 1) * 32);
                n11 = *(const float4*)(px1 + (kb + 1) * 32 + 4);
            }

            union { bf16x8 v; __hip_bfloat162 h2[4]; } c0, c1;
            c0.h2[0] = __float22bfloat162_rn(make_float2(a00.x, a00.y));
            c0.h2[1] = __float22bfloat162_rn(make_float2(a00.z, a00.w));
            c0.h2[2] = __float22bfloat162_rn(make_float2(a01.x, a01.y));
            c0.h2[3] = __float22bfloat162_rn(make_float2(a01.z, a01.w));
            c1.h2[0] = __float22bfloat162_rn(make_float2(a10.x, a10.y));
            c1.h2[1] = __float22bfloat162_rn(make_float2(a10.z, a10.w));
            c1.h2[2] = __float22bfloat162_rn(make_float2(a11.x, a11.y));
            c1.h2[3] = __float22bfloat162_rn(make_float2(a11.z, a11.w));
            bf16x8 a0 = c0.v, a1 = c1.v;

#pragma unroll
            for (int nt = 0; nt < 8; ++nt) {
                union { uint4 u; bf16x8 v; } wb;
                wb.u = wlds[(kb * 8 + nt) * 64 + lane];
                acc[0][nt] = __builtin_amdgcn_mfma_f32_16x16x32_bf16(a0, wb.v, acc[0][nt], 0, 0, 0);
                acc[1][nt] = __builtin_amdgcn_mfma_f32_16x16x32_bf16(a1, wb.v, acc[1][nt], 0, 0, 0);
            }

            if (kb < 7) { a00 = n00; a01 = n01; a10 = n10; a11 = n11; }
        }
    }

#pragma unroll
    for (int f = 0; f < 2; ++f)
#pragma unroll
        for (int r = 0; r < 4; ++r) {
            int rr = m0 + f * 16 + kgrp * 4 + r;
            if (rr < M_NODES) {
                unsigned short* hp = h + (size_t)rr * D_OUT_N + mrow;
#pragma unroll
                for (int nt = 0; nt < 8; ++nt)
                    hp[nt * 16] = f2bf(acc[f][nt][r]);
            }
        }

    // --- fused histogram tail (no dependence on GEMM results) ---
    const int epb = (N_EDGES + gridDim.x - 1) / gridDim.x;   // 2047
    const int e0  = blockIdx.x * epb;
    const int e1  = (e0 + epb < N_EDGES) ? e0 + epb : N_EDGES;
    for (int e = e0 + threadIdx.x; e < e1; e += 256)
        atomicAdd(&counts[dst[e] * PAD], 1);
}

// ---------------------------------------------------------------------------
// Single-launch exclusive scan (49 co-resident blocks, lookback on flags).
// counts padded (stride PAD); offsets dense; cursor padded.
// ---------------------------------------------------------------------------
__global__ __launch_bounds__(256) void scan_kernel(const int* __restrict__ counts,
                                                   int* __restrict__ offsets,
                                                   int* __restrict__ cursor,
                                                   int* __restrict__ partials,
                                                   int* __restrict__ flags) {
    __shared__ int wsum[4];
    __shared__ int carry_s;
    const int tid  = threadIdx.x;
    const int lane = tid & 63;
    const int wid  = tid >> 6;
    const int blk  = blockIdx.x;
    const int base = blk * 1024 + tid * 4;

    int v[4];
#pragma unroll
    for (int i = 0; i < 4; ++i)
        v[i] = (base + i < M_NODES) ? counts[(base + i) * PAD] : 0;
    int t = v[0] + v[1] + v[2] + v[3];

    int s = t;
#pragma unroll
    for (int d = 1; d < 64; d <<= 1) {
        int u = __shfl_up(s, d, 64);
        if (lane >= d) s += u;
    }
    if (lane == 63) wsum[wid] = s;
    __syncthreads();
    int wbase = 0;
#pragma unroll
    for (int w = 0; w < 4; ++w) wbase += (w < wid) ? wsum[w] : 0;
    int total = wsum[0] + wsum[1] + wsum[2] + wsum[3];

    if (tid == 0) {
        __hip_atomic_store(&partials[blk], total, __ATOMIC_RELAXED, __HIP_MEMORY_SCOPE_AGENT);
        __hip_atomic_store(&flags[blk], 1, __ATOMIC_RELEASE, __HIP_MEMORY_SCOPE_AGENT);
        if (blk == 0) offsets[M_NODES] = N_EDGES;
    }

    // lookback: wave 0 lanes < blk sum predecessors' partials
    if (wid == 0) {
        int val = 0;
        if (lane < blk) {
            while (__hip_atomic_load(&flags[lane], __ATOMIC_ACQUIRE, __HIP_MEMORY_SCOPE_AGENT) == 0) {}
            val = __hip_atomic_load(&partials[lane], __ATOMIC_RELAXED, __HIP_MEMORY_SCOPE_AGENT);
        }
#pragma unroll
        for (int d = 32; d > 0; d >>= 1) val += __shfl_xor(val, d, 64);
        if (lane == 0) carry_s = val;
    }
    __syncthreads();
    const int carry = carry_s;

    int run = carry + wbase + s - t;   // exclusive prefix for this thread's 4 nodes
#pragma unroll
    for (int i = 0; i < 4; ++i) {
        if (base + i < M_NODES) {
            offsets[base + i] = run;
            cursor[(base + i) * PAD] = run;
        }
        run += v[i];
    }
}

// ---------------------------------------------------------------------------
// Permute edges into CSR order (padded cursor).
// ---------------------------------------------------------------------------
__global__ __launch_bounds__(256) void fill_kernel(const int* __restrict__ src,
                                                   const int* __restrict__ dst,
                                                   const float* __restrict__ edge_w,
                                                   int* __restrict__ cursor,
                                                   int2* __restrict__ ep) {
    int e = blockIdx.x * blockDim.x + threadIdx.x;
    if (e >= N_EDGES) return;
    int d   = dst[e];
    int pos = atomicAdd(&cursor[d * PAD], 1);
    ep[pos] = make_int2(src[e], __float_as_int(edge_w[e]));
}

// ---------------------------------------------------------------------------
// Gather: out[i] = b + sum w_e * h_bf16[src_e]. 16 lanes/node, unroll 4.
// ---------------------------------------------------------------------------
__global__ __launch_bounds__(256) void gather_kernel(const unsigned short* __restrict__ h,
                                                     const int2* __restrict__ ep,
                                                     const int* __restrict__ offsets,
                                                     const float* __restrict__ b,
                                                     float* __restrict__ out) {
    int t    = blockIdx.x * blockDim.x + threadIdx.x;
    int node = t >> 4;
    int lane = t & 15;
    if (node >= M_NODES) return;
    int beg = offsets[node];
    int end = offsets[node + 1];

    float4 b0 = *(const float4*)&b[lane * 8];
    float4 b1 = *(const float4*)&b[lane * 8 + 4];
    float a[4][8];
#pragma unroll
    for (int u = 0; u < 4; ++u)
#pragma unroll
        for (int c = 0; c < 8; ++c) a[u][c] = 0.f;

    int j = beg;
    for (; j + 4 <= end; j += 4) {
        int2 e0 = ep[j], e1 = ep[j + 1], e2 = ep[j + 2], e3 = ep[j + 3];
        uint4 q0 = *(const uint4*)(h + (size_t)e0.x * D_OUT_N + lane * 8);
        uint4 q1 = *(const uint4*)(h + (size_t)e1.x * D_OUT_N + lane * 8);
        uint4 q2 = *(const uint4*)(h + (size_t)e2.x * D_OUT_N + lane * 8);
        uint4 q3 = *(const uint4*)(h + (size_t)e3.x * D_OUT_N + lane * 8);
        float w0 = __int_as_float(e0.y), w1 = __int_as_float(e1.y);
        float w2 = __int_as_float(e2.y), w3 = __int_as_float(e3.y);
        a[0][0] += w0 * bflo(q0.x);  a[0][1] += w0 * bfhi(q0.x);
        a[0][2] += w0 * bflo(q0.y);  a[0][3] += w0 * bfhi(q0.y);
        a[0][4] += w0 * bflo(q0.z);  a[0][5] += w0 * bfhi(q0.z);
        a[0][6] += w0 * bflo(q0.w);  a[0][7] += w0 * bfhi(q0.w);
        a[1][0] += w1 * bflo(q1.x);  a[1][1] += w1 * bfhi(q1.x);
        a[1][2] += w1 * bflo(q1.y);  a[1][3] += w1 * bfhi(q1.y);
        a[1][4] += w1 * bflo(q1.z);  a[1][5] += w1 * bfhi(q1.z);
        a[1][6] += w1 * bflo(q1.w);  a[1][7] += w1 * bfhi(q1.w);
        a[2][0] += w2 * bflo(q2.x);  a[2][1] += w2 * bfhi(q2.x);
        a[2][2] += w2 * bflo(q2.y);  a[2][3] += w2 * bfhi(q2.y);
        a[2][4] += w2 * bflo(q2.z);  a[2][5] += w2 * bfhi(q2.z);
        a[2][6] += w2 * bflo(q2.w);  a[2][7] += w2 * bfhi(q2.w);
        a[3][0] += w3 * bflo(q3.x);  a[3][1] += w3 * bfhi(q3.x);
        a[3][2] += w3 * bflo(q3.y);  a[3][3] += w3 * bfhi(q3.y);
        a[3][4] += w3 * bflo(q3.z);  a[3][5] += w3 * bfhi(q3.z);
        a[3][6] += w3 * bflo(q3.w);  a[3][7] += w3 * bfhi(q3.w);
    }
    for (; j < end; ++j) {
        int2 e0 = ep[j];
        float w0 = __int_as_float(e0.y);
        uint4 q0 = *(const uint4*)(h + (size_t)e0.x * D_OUT_N + lane * 8);
        a[0][0] += w0 * bflo(q0.x);  a[0][1] += w0 * bfhi(q0.x);
        a[0][2] += w0 * bflo(q0.y);  a[0][3] += w0 * bfhi(q0.y);
        a[0][4] += w0 * bflo(q0.z);  a[0][5] += w0 * bfhi(q0.z);
        a[0][6] += w0 * bflo(q0.w);  a[0][7] += w0 * bfhi(q0.w);
    }

    float4 o0 = make_float4(b0.x + a[0][0] + a[1][0] + a[2][0] + a[3][0],
                            b0.y + a[0][1] + a[1][1] + a[2][1] + a[3][1],
                            b0.z + a[0][2] + a[1][2] + a[2][2] + a[3][2],
                            b0.w + a[0][3] + a[1][3] + a[2][3] + a[3][3]);
    float4 o1 = make_float4(b1.x + a[0][4] + a[1][4] + a[2][4] + a[3][4],
                            b1.y + a[0][5] + a[1][5] + a[2][5] + a[3][5],
                            b1.z + a[0][6] + a[1][6] + a[2][6] + a[3][6],
                            b1.w + a[0][7] + a[1][7] + a[2][7] + a[3][7]);
    float* op = &out[(size_t)node * D_OUT_N + lane * 8];
    *(float4*)op = o0;
    *(float4*)(op + 4) = o1;
}

extern "C" void kernel_launch(void* const* d_in, const int* in_sizes, int n_in,
                              void* d_out, int out_size, void* d_ws, size_t ws_size,
                              hipStream_t stream) {
    const float* x      = (const float*)d_in[0];
    const float* edge_w = (const float*)d_in[1];
    const int*   src    = (const int*)d_in[2];
    const int*   dst    = (const int*)d_in[3];
    const float* W      = (const float*)d_in[4];
    const float* b      = (const float*)d_in[5];
    float* out = (float*)d_out;

    char* wsp = (char*)d_ws;
    unsigned short* h = (unsigned short*)wsp;  wsp += (size_t)M_NODES * D_OUT_N * 2;      // 12.8 MB
    int*   counts   = (int*)wsp;         wsp += (size_t)M_NODES * PAD * 4;                // 3.2 MB (padded)
    int*   flags    = (int*)wsp;         wsp += 64 * 4;                                   // 256 B (zeroed w/ counts)
    int*   cursor   = (int*)wsp;         wsp += (size_t)M_NODES * PAD * 4;                // 3.2 MB (padded)
    int*   offsets  = (int*)wsp;         wsp += (((size_t)M_NODES + 1) * 4 + 15) & ~15ull;
    int2*  ep       = (int2*)wsp;        wsp += (size_t)N_EDGES * 8;                      // 6.4 MB
    unsigned short* Wp = (unsigned short*)wsp; wsp += (size_t)16 * 8 * 64 * 8 * 2;        // 128 KB
    int*   partials = (int*)wsp;         wsp += (SCAN_NBLK * 4 + 15) & ~15ull;

    // zero counts + flags in one async memset (graph-capture legal)
    hipMemsetAsync(counts, 0, (size_t)M_NODES * PAD * 4 + 64 * 4, stream);
    permw_kernel<<<32, 256, 0, stream>>>(W, Wp);
    mfma_gemm_hist_kernel<<<(M_NODES + 127) / 128, 256, 0, stream>>>(
        x, (const uint4*)Wp, h, dst, counts);
    scan_kernel<<<SCAN_NBLK, 256, 0, stream>>>(counts, offsets, cursor, partials, flags);
    fill_kernel<<<(N_EDGES + 255) / 256, 256, 0, stream>>>(src, dst, edge_w, cursor, ep);
    gather_kernel<<<(int)(((long long)M_NODES * 16 + 255) / 256), 256, 0, stream>>>(
        h, ep, offsets, b, out);
}